// Round 2
// baseline (136.232 us; speedup 1.0000x reference)
//
#include <hip/hip_runtime.h>
#include <hip/hip_bf16.h>
#include <math.h>

// FieldTypedProjector: per-token Fourier features -> per-kind 2-layer MLP (exact GELU)
//   out[t] = W2[k]^T gelu(W1[k]^T ff(v_t) + b1[k]) + b2[k] + kind_emb[k]
// Strategy: bucket tokens by kind, pack weights to bf16 MFMA fragment order,
// one fused MFMA kernel per 64-token tile.
// R1 fix: all scratch in static __device__ arrays (R0 overflowed d_ws and
// corrupted the harness's pristine input copies -> wrong on every call but the first).

#define NK 8
#define DM 256
#define TMAX 65536     // N*S = 32*2048 (fixed by setup_inputs)
#define K1 64          // 2*24 Fourier features padded 48 -> 64
#define W1PK 16384     // per-kind packed W1 elements (64*256)
#define W2PK 65536     // per-kind packed W2 elements (256*256)

typedef __attribute__((ext_vector_type(8))) short   s16x8;
typedef __attribute__((ext_vector_type(8))) __bf16  bf16x8;
typedef __attribute__((ext_vector_type(4))) float   f32x4;

// Static device scratch — independent of ws_size, rewritten every call.
__device__ int   g_counts[NK];
__device__ int   g_bucket[(size_t)NK * TMAX];
__device__ short g_W1p[(size_t)NK * W1PK];
__device__ short g_W2p[(size_t)NK * W2PK];

static __device__ __forceinline__ short f2bf(float f) {
    __hip_bfloat16 h = __float2bfloat16(f);
    return __builtin_bit_cast(short, h);
}

static __device__ __forceinline__ f32x4 mfma16(s16x8 a, s16x8 b, f32x4 c) {
    return __builtin_amdgcn_mfma_f32_16x16x32_bf16(
        __builtin_bit_cast(bf16x8, a), __builtin_bit_cast(bf16x8, b), c, 0, 0, 0);
}

// ---------------- pack W1/W2 to bf16 MFMA B-fragment order --------------------
// B-frag (16x16x32): lane l holds B[k = (l>>4)*8 + j][n = l&15], j=0..7 contiguous.
// group g within kind = (ktile*16 + ntile)*64 + lane; element = g*8 + j.
// Block 0 also zeroes g_counts (this kernel runs before bucket_kernel).
__global__ void pack_kernel(const float* __restrict__ W1, const float* __restrict__ W2) {
    if (blockIdx.x == 0 && threadIdx.x < NK) g_counts[threadIdx.x] = 0;
    int p = blockIdx.x * 256 + threadIdx.x;
    const int PER_KIND = 2048 + 8192;     // W1 groups + W2 groups
    if (p >= NK * PER_KIND) return;
    int kind = p / PER_KIND;
    int rem  = p % PER_KIND;
    s16x8 v;
    if (rem < 2048) {                      // W1: K1=64 -> 2 ktiles * 16 ntiles * 64 lanes
        int g = rem;
        int ktile = g >> 10, ntile = (g >> 6) & 15, lane = g & 63;
        int kk0 = ktile * 32 + (lane >> 4) * 8;
        int n   = ntile * 16 + (lane & 15);
        #pragma unroll
        for (int j = 0; j < 8; ++j) {
            int kk = kk0 + j;
            float f = (kk < 48) ? W1[((size_t)kind * 48 + kk) * DM + n] : 0.0f;
            v[j] = f2bf(f);
        }
        *(s16x8*)(g_W1p + (size_t)kind * W1PK + (size_t)g * 8) = v;
    } else {                               // W2: 8 ktiles * 16 ntiles * 64 lanes
        int g = rem - 2048;
        int ktile = g >> 10, ntile = (g >> 6) & 15, lane = g & 63;
        int kk0 = ktile * 32 + (lane >> 4) * 8;
        int n   = ntile * 16 + (lane & 15);
        #pragma unroll
        for (int j = 0; j < 8; ++j)
            v[j] = f2bf(W2[((size_t)kind * DM + kk0 + j) * DM + n]);
        *(s16x8*)(g_W2p + (size_t)kind * W2PK + (size_t)g * 8) = v;
    }
}

// ---------------- bucket tokens by kind (block-aggregated atomics) ------------
__global__ void bucket_kernel(const int* __restrict__ kinds, int T) {
    __shared__ int wcnt[4][NK];   // per-wave per-kind counts -> exclusive wave prefix
    __shared__ int base[NK];      // block's global base per kind
    const int tid = threadIdx.x, wave = tid >> 6, lane = tid & 63;
    int t = blockIdx.x * 256 + tid;
    int k = (t < T) ? kinds[t] : -1;
    int myrank = 0;
    #pragma unroll
    for (int kk = 0; kk < NK; ++kk) {
        unsigned long long m = __ballot(k == kk);
        if (lane == 0) wcnt[wave][kk] = __popcll(m);
        if (k == kk) myrank = __popcll(m & ((1ull << lane) - 1ull));
    }
    __syncthreads();
    if (tid < NK) {
        int s = 0;
        #pragma unroll
        for (int w = 0; w < 4; ++w) { int c = wcnt[w][tid]; wcnt[w][tid] = s; s += c; }
        base[tid] = atomicAdd(&g_counts[tid], s);
    }
    __syncthreads();
    if (k >= 0)
        g_bucket[(size_t)k * T + base[k] + wcnt[wave][k] + myrank] = t;
}

// ---------------- fused MLP: 64-token tile of one kind ------------------------
__global__ __launch_bounds__(256) void fproj_gemm(
    const float* __restrict__ values, const float* __restrict__ Bmat,
    const float* __restrict__ kind_emb, const float* __restrict__ b1,
    const float* __restrict__ b2, float* __restrict__ out, int T)
{
    const int k   = blockIdx.y;
    const int cnt = g_counts[k];
    const int m0  = blockIdx.x * 64;
    if (m0 >= cnt) return;
    const int valid = min(64, cnt - m0);

    __shared__ short Apack[4096];      // ff 64x64 in A-frag order (2 ktiles x 4 mtiles)
    __shared__ short Hpack[16384];     // h  64x256 in A-frag order (8 ktiles x 4 mtiles)
    __shared__ int   toks[64];
    __shared__ float vals[64];

    const int tid  = threadIdx.x;
    const int wave = tid >> 6;
    const int lane = tid & 63;
    const int quad = lane >> 4;
    const int cl   = lane & 15;

    if (tid < 64) {
        int t = -1; float v = 0.0f;
        if (tid < valid) { t = g_bucket[(size_t)k * T + m0 + tid]; v = values[t]; }
        toks[tid] = t; vals[tid] = v;
    }
    __syncthreads();

    // Fourier features -> Apack (A-frag layout): kk<24: sin, kk<48: cos, else 0
    for (int idx = tid; idx < 4096; idx += 256) {
        int m = idx >> 6, kk = idx & 63;
        float f = 0.0f;
        if (kk < 48) {
            int b = (kk < 24) ? kk : kk - 24;
            float y = 6.283185307179586f * vals[m] * Bmat[b];
            f = (kk < 24) ? __sinf(y) : __cosf(y);
        }
        int mt = m >> 4, kt = kk >> 5, q = (kk >> 3) & 3, j = kk & 7;
        int l = (m & 15) | (q << 4);
        Apack[((kt * 4 + mt) << 9) + (l << 3) + j] = f2bf(f);
    }
    __syncthreads();

    // ---- GEMM1: [64 x K1=64] x [K1 x 256], this wave covers cols [wave*64, +64)
    f32x4 acc[4][4];
    #pragma unroll
    for (int mt = 0; mt < 4; ++mt)
        #pragma unroll
        for (int nt = 0; nt < 4; ++nt) acc[mt][nt] = (f32x4){0.f, 0.f, 0.f, 0.f};

    const s16x8* Ap  = (const s16x8*)Apack;
    const s16x8* B1p = (const s16x8*)(g_W1p + (size_t)k * W1PK);
    #pragma unroll
    for (int kt = 0; kt < 2; ++kt) {
        s16x8 a[4], b[4];
        #pragma unroll
        for (int mt = 0; mt < 4; ++mt) a[mt] = Ap[(kt * 4 + mt) * 64 + lane];
        #pragma unroll
        for (int nt = 0; nt < 4; ++nt) b[nt] = B1p[(kt * 16 + wave * 4 + nt) * 64 + lane];
        #pragma unroll
        for (int mt = 0; mt < 4; ++mt)
            #pragma unroll
            for (int nt = 0; nt < 4; ++nt) acc[mt][nt] = mfma16(a[mt], b[nt], acc[mt][nt]);
    }

    // ---- bias + exact GELU, write h to Hpack in A-frag layout (m=row, k2=col)
    #pragma unroll
    for (int nt = 0; nt < 4; ++nt) {
        int c = wave * 64 + nt * 16 + cl;
        float bias = b1[k * DM + c];
        int kt2 = c >> 5, q2 = (c >> 3) & 3, j2 = c & 7;
        #pragma unroll
        for (int mt = 0; mt < 4; ++mt)
            #pragma unroll
            for (int r4 = 0; r4 < 4; ++r4) {
                int r = mt * 16 + quad * 4 + r4;
                float x = acc[mt][nt][r4] + bias;
                float h = 0.5f * x * (1.0f + erff(x * 0.7071067811865476f));
                int l2 = (r & 15) | (q2 << 4);
                Hpack[((kt2 * 4 + (r >> 4)) << 9) + (l2 << 3) + j2] = f2bf(h);
            }
    }
    __syncthreads();

    // ---- GEMM2: [64 x 256] x [256 x 256], this wave covers cols [wave*64, +64)
    f32x4 acc2[4][4];
    #pragma unroll
    for (int mt = 0; mt < 4; ++mt)
        #pragma unroll
        for (int nt = 0; nt < 4; ++nt) acc2[mt][nt] = (f32x4){0.f, 0.f, 0.f, 0.f};

    const s16x8* Hp  = (const s16x8*)Hpack;
    const s16x8* B2p = (const s16x8*)(g_W2p + (size_t)k * W2PK);
    #pragma unroll
    for (int kt = 0; kt < 8; ++kt) {
        s16x8 a[4], b[4];
        #pragma unroll
        for (int mt = 0; mt < 4; ++mt) a[mt] = Hp[(kt * 4 + mt) * 64 + lane];
        #pragma unroll
        for (int nt = 0; nt < 4; ++nt) b[nt] = B2p[(kt * 16 + wave * 4 + nt) * 64 + lane];
        #pragma unroll
        for (int mt = 0; mt < 4; ++mt)
            #pragma unroll
            for (int nt = 0; nt < 4; ++nt) acc2[mt][nt] = mfma16(a[mt], b[nt], acc2[mt][nt]);
    }

    // ---- epilogue: + b2 + kind_emb, scatter rows to out
    #pragma unroll
    for (int nt = 0; nt < 4; ++nt) {
        int c = wave * 64 + nt * 16 + cl;
        float add = b2[k * DM + c] + kind_emb[k * DM + c];
        #pragma unroll
        for (int mt = 0; mt < 4; ++mt)
            #pragma unroll
            for (int r4 = 0; r4 < 4; ++r4) {
                int r = mt * 16 + quad * 4 + r4;
                if (r < valid)
                    out[(size_t)toks[r] * DM + c] = acc2[mt][nt][r4] + add;
            }
    }
}

extern "C" void kernel_launch(void* const* d_in, const int* in_sizes, int n_in,
                              void* d_out, int out_size, void* d_ws, size_t ws_size,
                              hipStream_t stream) {
    const float* values   = (const float*)d_in[0];
    const int*   kinds    = (const int*)  d_in[1];
    const float* Bmat     = (const float*)d_in[2];
    const float* kind_emb = (const float*)d_in[3];
    const float* W1       = (const float*)d_in[4];
    const float* b1       = (const float*)d_in[5];
    const float* W2       = (const float*)d_in[6];
    const float* b2       = (const float*)d_in[7];
    float* out = (float*)d_out;
    const int T = in_sizes[0];   // 65536

    pack_kernel<<<dim3((NK * (2048 + 8192) + 255) / 256), dim3(256), 0, stream>>>(W1, W2);
    bucket_kernel<<<dim3((T + 255) / 256), dim3(256), 0, stream>>>(kinds, T);
    dim3 g((T + 63) / 64, NK);
    fproj_gemm<<<g, dim3(256), 0, stream>>>(values, Bmat, kind_emb, b1, b2, out, T);
}